// Round 2
// baseline (751.509 us; speedup 1.0000x reference)
//
#include <hip/hip_runtime.h>
#include <hip/hip_bf16.h>

#define S_LEN 2048
#define HID   4096
#define NH    32
#define NKV   8
#define HD    128
#define QKV_N 6144
#define KDIM  4096

typedef __attribute__((ext_vector_type(8))) short short8;
typedef __attribute__((ext_vector_type(4))) float floatx4;
typedef unsigned short ushort;

__device__ __forceinline__ unsigned short f2bu(float f) {
  __hip_bfloat16 b = __float2bfloat16(f);
  return *reinterpret_cast<unsigned short*>(&b);
}
__device__ __forceinline__ void store_c(float* p, float v) { *p = v; }
__device__ __forceinline__ void store_c(__hip_bfloat16* p, float v) { *p = __float2bfloat16(v); }

__device__ __forceinline__ void async_copy16(const void* g, void* l) {
  __builtin_amdgcn_global_load_lds((const __attribute__((address_space(1))) void*)g,
                                   (__attribute__((address_space(3))) void*)l, 16, 0, 0);
}

// ---------------- fp32 -> bf16 convert ----------------
struct bf16x4 { __hip_bfloat16 a, b, c, d; };
__global__ void cvt_f32_bf16(const float* __restrict__ src, __hip_bfloat16* __restrict__ dst, int n4) {
  int i = blockIdx.x * blockDim.x + threadIdx.x;
  if (i < n4) {
    float4 v = ((const float4*)src)[i];
    bf16x4 o = { __float2bfloat16(v.x), __float2bfloat16(v.y),
                 __float2bfloat16(v.z), __float2bfloat16(v.w) };
    ((bf16x4*)dst)[i] = o;
  }
}

// ---------------- NT bf16 GEMM with global_load_lds staging (m97 structure) ----------------
// C[M][N] = sum_k A[m][k]*B[n][k]
template <typename CT>
__global__ __launch_bounds__(256, 2) void gemm_nt(const __hip_bfloat16* __restrict__ A,
                                                  const __hip_bfloat16* __restrict__ B,
                                                  CT* __restrict__ C, int M, int N, int K) {
  __shared__ __align__(16) ushort As[128 * 32];
  __shared__ __align__(16) ushort Bs[128 * 32];
  const int tid  = threadIdx.x;
  const int bm   = blockIdx.y * 128;
  const int bn   = blockIdx.x * 128;
  const int wave = tid >> 6;
  const int lane = tid & 63;
  const int ww   = (wave >> 1) * 64;   // wave row offset in C tile
  const int wc   = (wave & 1) * 64;    // wave col offset
  const int l15  = lane & 15;
  const int quad = lane >> 4;

  const ushort* Au = (const ushort*)A;
  const ushort* Bu = (const ushort*)B;

  // staging addresses: wave w stages rows [w*32, w*32+32) of both tiles,
  // one global_load_lds(16B) covers 16 rows (lane>>2 = row, (lane&3)*8 = k-offset)
  const int srow  = lane >> 2;
  const int scol  = (lane & 3) * 8;
  const ushort* Ag0 = Au + (size_t)(bm + wave * 32 + srow) * K + scol;
  const ushort* Ag1 = Au + (size_t)(bm + wave * 32 + 16 + srow) * K + scol;
  const ushort* Bg0 = Bu + (size_t)(bn + wave * 32 + srow) * K + scol;
  const ushort* Bg1 = Bu + (size_t)(bn + wave * 32 + 16 + srow) * K + scol;
  ushort* Al0 = &As[(wave * 32) * 32];
  ushort* Al1 = &As[(wave * 32 + 16) * 32];
  ushort* Bl0 = &Bs[(wave * 32) * 32];
  ushort* Bl1 = &Bs[(wave * 32 + 16) * 32];

  floatx4 acc[4][4] = {};

  for (int k0 = 0; k0 < K; k0 += 32) {
    __syncthreads();                 // everyone done reading previous tile
    async_copy16(Ag0 + k0, Al0);
    async_copy16(Ag1 + k0, Al1);
    async_copy16(Bg0 + k0, Bl0);
    async_copy16(Bg1 + k0, Bl1);
    __syncthreads();                 // vmcnt(0) drained -> tile ready
    short8 af[4], bf[4];
#pragma unroll
    for (int i = 0; i < 4; ++i) {
      af[i] = *(const short8*)&As[(ww + i * 16 + l15) * 32 + quad * 8];
      bf[i] = *(const short8*)&Bs[(wc + i * 16 + l15) * 32 + quad * 8];
    }
#pragma unroll
    for (int mi = 0; mi < 4; ++mi)
#pragma unroll
      for (int ni = 0; ni < 4; ++ni)
        acc[mi][ni] = __builtin_amdgcn_mfma_f32_16x16x32_bf16(af[mi], bf[ni], acc[mi][ni], 0, 0, 0);
  }
#pragma unroll
  for (int mi = 0; mi < 4; ++mi)
#pragma unroll
    for (int ni = 0; ni < 4; ++ni)
#pragma unroll
      for (int r = 0; r < 4; ++r) {
        int row = bm + ww + mi * 16 + quad * 4 + r;  // C/D: row=(lane>>4)*4+reg
        int col = bn + wc + ni * 16 + l15;           //      col=lane&15
        store_c(&C[(size_t)row * N + col], acc[mi][ni][r]);
      }
}

// ---------------- RoPE for q,k -> head-major layouts ----------------
__global__ void rope_qk(const __hip_bfloat16* __restrict__ QKV,
                        const float* __restrict__ cosp, const float* __restrict__ sinp,
                        __hip_bfloat16* __restrict__ Qh, __hip_bfloat16* __restrict__ Kh) {
  int s = blockIdx.y;
  int col = blockIdx.x * 256 + threadIdx.x;  // 0..5119 (q then k region)
  if (col >= 5120) return;
  const size_t base = (size_t)s * QKV_N;
  float x = __bfloat162float(QKV[base + col]);
  int dd = col & 127;
  float val;
  if (dd < 64) {
    float xp = __bfloat162float(QKV[base + col + 64]);
    val = x * cosp[s * 64 + dd] - xp * sinp[s * 64 + dd];
  } else {
    int f = dd - 64;
    float xp = __bfloat162float(QKV[base + col - 64]);
    val = x * cosp[s * 64 + f] + xp * sinp[s * 64 + f];
  }
  if (col < HID) {
    int h = col >> 7;
    Qh[((size_t)h * S_LEN + s) * HD + dd] = __float2bfloat16(val);
  } else {
    int h = (col - HID) >> 7;
    Kh[((size_t)h * S_LEN + s) * HD + dd] = __float2bfloat16(val);
  }
}

// ---------------- V transpose: QKV[s][5120+h*128+d] -> Vt[h][d][s] ----------------
__global__ void v_transpose(const __hip_bfloat16* __restrict__ QKV, __hip_bfloat16* __restrict__ Vt) {
  __shared__ ushort tile[64][130];
  int h = blockIdx.y;
  int s0 = blockIdx.x * 64;
  int t = threadIdx.x;
  const ushort* src = (const ushort*)QKV;
#pragma unroll
  for (int i = 0; i < 32; ++i) {
    int flat = i * 256 + t;
    int r = flat >> 7, c = flat & 127;
    tile[r][c] = src[(size_t)(s0 + r) * QKV_N + 5120 + h * 128 + c];
  }
  __syncthreads();
  ushort* dst = (ushort*)Vt;
#pragma unroll
  for (int i = 0; i < 8; ++i) {
    int g = i * 256 + t;
    int d = g >> 4, j4 = (g & 15) * 4;
    ushort4 o;
    o.x = tile[j4][d]; o.y = tile[j4 + 1][d]; o.z = tile[j4 + 2][d]; o.w = tile[j4 + 3][d];
    *(ushort4*)&dst[((size_t)h * HD + d) * S_LEN + s0 + j4] = o;
  }
}

// ---------------- flash attention v2 ----------------
// 16 q-rows per wave, 64-key steps, heavy-tile-first block order, per-wave P in LDS (stride 72).
__global__ __launch_bounds__(256, 3) void attn(const __hip_bfloat16* __restrict__ Qh,
                                               const __hip_bfloat16* __restrict__ Kh,
                                               const __hip_bfloat16* __restrict__ Vt,
                                               __hip_bfloat16* __restrict__ AO) {
  __shared__ __align__(16) ushort P[4][16][72];
  const int b = blockIdx.x;
  const int h = b & 31;
  const int qt = 31 - (b >> 5);            // heavy tiles dispatched first
  const int wave = threadIdx.x >> 6;
  const int lane = threadIdx.x & 63;
  const int l15 = lane & 15, quad = lane >> 4;
  const int q0 = qt * 64 + wave * 16;      // this wave's 16 q rows
  const int hk = h & 7;                    // jnp.tile => kv head = h % NKV
  const ushort* Qu = (const ushort*)Qh + (size_t)h * S_LEN * HD;
  const ushort* Ku = (const ushort*)Kh + (size_t)hk * S_LEN * HD;
  const ushort* Vu = (const ushort*)Vt + (size_t)hk * HD * S_LEN;

  short8 qf[4];
#pragma unroll
  for (int kd = 0; kd < 4; ++kd)
    qf[kd] = *(const short8*)(Qu + (size_t)(q0 + l15) * HD + kd * 32 + quad * 8);

  floatx4 o[8] = {};
  float mst[4], lsum[4];
#pragma unroll
  for (int r = 0; r < 4; ++r) { mst[r] = -1e30f; lsum[r] = 0.f; }

  const float scale = 0.08838834764831845f;
  const int jend = q0 + 16;

  for (int j0 = 0; j0 < jend; j0 += 64) {
    floatx4 sc[4] = {};
    // QK^T over 64 keys, kf loaded in two 32-key halves to cap registers
#pragma unroll
    for (int half = 0; half < 2; ++half) {
      short8 kf[2][4];
#pragma unroll
      for (int nt = 0; nt < 2; ++nt)
#pragma unroll
        for (int kd = 0; kd < 4; ++kd)
          kf[nt][kd] = *(const short8*)(Ku + (size_t)(j0 + half * 32 + nt * 16 + l15) * HD + kd * 32 + quad * 8);
#pragma unroll
      for (int nt = 0; nt < 2; ++nt)
#pragma unroll
        for (int kd = 0; kd < 4; ++kd)
          sc[half * 2 + nt] = __builtin_amdgcn_mfma_f32_16x16x32_bf16(qf[kd], kf[nt][kd], sc[half * 2 + nt], 0, 0, 0);
    }
    // online softmax, rows q0 + quad*4 + r
#pragma unroll
    for (int r = 0; r < 4; ++r) {
      const int row = q0 + quad * 4 + r;
      float v[4];
#pragma unroll
      for (int nt = 0; nt < 4; ++nt) {
        float x = sc[nt][r] * scale;
        if (j0 + nt * 16 + l15 > row) x = -1e30f;
        v[nt] = x;
      }
      float vm = fmaxf(fmaxf(v[0], v[1]), fmaxf(v[2], v[3]));
      vm = fmaxf(vm, __shfl_xor(vm, 1));
      vm = fmaxf(vm, __shfl_xor(vm, 2));
      vm = fmaxf(vm, __shfl_xor(vm, 4));
      vm = fmaxf(vm, __shfl_xor(vm, 8));
      float mnew = fmaxf(mst[r], vm);
      float alpha = __expf(mst[r] - mnew);
      float ps = 0.f;
#pragma unroll
      for (int nt = 0; nt < 4; ++nt) {
        float p = __expf(v[nt] - mnew);
        ps += p;
        P[wave][quad * 4 + r][nt * 16 + l15] = f2bu(p);
      }
      ps += __shfl_xor(ps, 1);
      ps += __shfl_xor(ps, 2);
      ps += __shfl_xor(ps, 4);
      ps += __shfl_xor(ps, 8);
      lsum[r] = lsum[r] * alpha + ps;
      mst[r] = mnew;
#pragma unroll
      for (int t = 0; t < 8; ++t) o[t][r] *= alpha;
    }
    asm volatile("s_waitcnt lgkmcnt(0)" ::: "memory");
    short8 pf[2];
    pf[0] = *(const short8*)&P[wave][l15][quad * 8];
    pf[1] = *(const short8*)&P[wave][l15][32 + quad * 8];
    // PV: o[t] += P(16x64) x V(64x128)
#pragma unroll
    for (int t = 0; t < 8; ++t) {
      const ushort* vrow = Vu + (size_t)(t * 16 + l15) * S_LEN + j0;
      short8 vf0 = *(const short8*)(vrow + quad * 8);
      short8 vf1 = *(const short8*)(vrow + 32 + quad * 8);
      o[t] = __builtin_amdgcn_mfma_f32_16x16x32_bf16(pf[0], vf0, o[t], 0, 0, 0);
      o[t] = __builtin_amdgcn_mfma_f32_16x16x32_bf16(pf[1], vf1, o[t], 0, 0, 0);
    }
  }
#pragma unroll
  for (int r = 0; r < 4; ++r) {
    const int row = q0 + quad * 4 + r;
    const float inv = 1.0f / lsum[r];
#pragma unroll
    for (int t = 0; t < 8; ++t)
      AO[(size_t)row * HID + h * HD + t * 16 + l15] = __float2bfloat16(o[t][r] * inv);
  }
}

extern "C" void kernel_launch(void* const* d_in, const int* in_sizes, int n_in,
                              void* d_out, int out_size, void* d_ws, size_t ws_size,
                              hipStream_t stream) {
  const float* x    = (const float*)d_in[0];
  const float* wq   = (const float*)d_in[1];
  const float* wk   = (const float*)d_in[2];
  const float* wv   = (const float*)d_in[3];
  const float* wo   = (const float*)d_in[4];
  const float* cosp = (const float*)d_in[5];
  const float* sinp = (const float*)d_in[6];
  float* out = (float*)d_out;

  char* ws = (char*)d_ws;
  size_t off = 0;
  auto alloc = [&](size_t bytes) { char* p = ws + off; off += (bytes + 255) & ~255ull; return p; };
  __hip_bfloat16* Xb   = (__hip_bfloat16*)alloc((size_t)S_LEN * KDIM * 2);
  __hip_bfloat16* Wqkv = (__hip_bfloat16*)alloc((size_t)QKV_N * KDIM * 2);
  __hip_bfloat16* Wob  = (__hip_bfloat16*)alloc((size_t)HID * HID * 2);
  __hip_bfloat16* QKVb = (__hip_bfloat16*)alloc((size_t)S_LEN * QKV_N * 2);
  __hip_bfloat16* Qh   = (__hip_bfloat16*)alloc((size_t)NH * S_LEN * HD * 2);
  __hip_bfloat16* Kh   = (__hip_bfloat16*)alloc((size_t)NKV * S_LEN * HD * 2);
  __hip_bfloat16* Vt   = (__hip_bfloat16*)alloc((size_t)NKV * HD * S_LEN * 2);
  __hip_bfloat16* AO   = (__hip_bfloat16*)alloc((size_t)S_LEN * HID * 2);

  auto cvt = [&](const float* s, __hip_bfloat16* dpt, size_t n) {
    int n4 = (int)(n / 4);
    cvt_f32_bf16<<<dim3((n4 + 255) / 256), dim3(256), 0, stream>>>(s, dpt, n4);
  };
  cvt(x, Xb, (size_t)S_LEN * KDIM);
  cvt(wq, Wqkv, (size_t)HID * KDIM);
  cvt(wk, Wqkv + (size_t)HID * KDIM, (size_t)NKV * HD * KDIM);
  cvt(wv, Wqkv + (size_t)(HID + NKV * HD) * KDIM, (size_t)NKV * HD * KDIM);
  cvt(wo, Wob, (size_t)HID * HID);

  gemm_nt<__hip_bfloat16><<<dim3(QKV_N / 128, S_LEN / 128), dim3(256), 0, stream>>>(
      Xb, Wqkv, QKVb, S_LEN, QKV_N, KDIM);
  rope_qk<<<dim3(20, S_LEN), dim3(256), 0, stream>>>(QKVb, cosp, sinp, Qh, Kh);
  v_transpose<<<dim3(S_LEN / 64, NKV), dim3(256), 0, stream>>>(QKVb, Vt);
  attn<<<dim3(32 * 32), dim3(256), 0, stream>>>(Qh, Kh, Vt, AO);
  gemm_nt<float><<<dim3(HID / 128, S_LEN / 128), dim3(256), 0, stream>>>(
      AO, Wob, out, S_LEN, KDIM, KDIM);
}

// Round 3
// 572.449 us; speedup vs baseline: 1.3128x; 1.3128x over previous
//
#include <hip/hip_runtime.h>
#include <hip/hip_bf16.h>

#define S_LEN 2048
#define HID   4096
#define NH    32
#define NKV   8
#define HD    128
#define QKV_N 6144
#define KDIM  4096

typedef __attribute__((ext_vector_type(8))) short short8;
typedef __attribute__((ext_vector_type(4))) float floatx4;
typedef unsigned short ushort;

__device__ __forceinline__ unsigned short f2bu(float f) {
  __hip_bfloat16 b = __float2bfloat16(f);
  return *reinterpret_cast<unsigned short*>(&b);
}
__device__ __forceinline__ void store_c(float* p, float v) { *p = v; }
__device__ __forceinline__ void store_c(__hip_bfloat16* p, float v) { *p = __float2bfloat16(v); }

__device__ __forceinline__ void async_copy16(const void* g, void* l) {
  __builtin_amdgcn_global_load_lds((const __attribute__((address_space(1))) void*)g,
                                   (__attribute__((address_space(3))) void*)l, 16, 0, 0);
}

// ---------------- fp32 -> bf16 convert ----------------
struct bf16x4 { __hip_bfloat16 a, b, c, d; };
__global__ void cvt_f32_bf16(const float* __restrict__ src, __hip_bfloat16* __restrict__ dst, int n4) {
  int i = blockIdx.x * blockDim.x + threadIdx.x;
  if (i < n4) {
    float4 v = ((const float4*)src)[i];
    bf16x4 o = { __float2bfloat16(v.x), __float2bfloat16(v.y),
                 __float2bfloat16(v.z), __float2bfloat16(v.w) };
    ((bf16x4*)dst)[i] = o;
  }
}

// ---------------- NT bf16 GEMM, BK=64, swizzled LDS, global_load_lds staging ----------------
// C[M][N] = sum_k A[m][k]*B[n][k].  LDS[row][chunk c] holds global chunk c^(row&7) (chunk=8 shorts).
template <typename CT>
__global__ __launch_bounds__(256, 2) void gemm_nt(const __hip_bfloat16* __restrict__ A,
                                                  const __hip_bfloat16* __restrict__ B,
                                                  CT* __restrict__ C, int M, int N, int K) {
  __shared__ __align__(16) ushort As[128 * 64];
  __shared__ __align__(16) ushort Bs[128 * 64];
  const int tid  = threadIdx.x;
  const int bm   = blockIdx.y * 128;
  const int bn   = blockIdx.x * 128;
  const int wave = tid >> 6;
  const int lane = tid & 63;
  const int ww   = (wave >> 1) * 64;
  const int wc   = (wave & 1) * 64;
  const int l15  = lane & 15;
  const int quad = lane >> 4;

  const ushort* Au = (const ushort*)A;
  const ushort* Bu = (const ushort*)B;

  // staging: wave stages rows [wave*32, wave*32+32) of each tile, 4 issues x 8 rows x 128B.
  const int rr  = lane >> 3;          // 0..7 row within issue
  const int cc  = lane & 7;           // LDS chunk
  const int gch = cc ^ rr;            // global chunk (rows per issue start at multiple of 8)
  const ushort* Ag = Au + (size_t)(bm + wave * 32 + rr) * K + gch * 8;
  const ushort* Bg = Bu + (size_t)(bn + wave * 32 + rr) * K + gch * 8;

  floatx4 acc[4][4] = {};

  for (int k0 = 0; k0 < K; k0 += 64) {
    __syncthreads();
#pragma unroll
    for (int e = 0; e < 4; ++e) {
      async_copy16(Ag + (size_t)(e * 8) * K + k0, &As[(wave * 32 + e * 8) * 64]);
      async_copy16(Bg + (size_t)(e * 8) * K + k0, &Bs[(wave * 32 + e * 8) * 64]);
    }
    __syncthreads();
#pragma unroll
    for (int kd = 0; kd < 2; ++kd) {
      short8 af[4], bf[4];
#pragma unroll
      for (int i = 0; i < 4; ++i) {
        af[i] = *(const short8*)&As[(ww + i * 16 + l15) * 64 + ((kd * 4 + quad) ^ (l15 & 7)) * 8];
        bf[i] = *(const short8*)&Bs[(wc + i * 16 + l15) * 64 + ((kd * 4 + quad) ^ (l15 & 7)) * 8];
      }
#pragma unroll
      for (int mi = 0; mi < 4; ++mi)
#pragma unroll
        for (int ni = 0; ni < 4; ++ni)
          acc[mi][ni] = __builtin_amdgcn_mfma_f32_16x16x32_bf16(af[mi], bf[ni], acc[mi][ni], 0, 0, 0);
    }
  }
#pragma unroll
  for (int mi = 0; mi < 4; ++mi)
#pragma unroll
    for (int ni = 0; ni < 4; ++ni)
#pragma unroll
      for (int r = 0; r < 4; ++r) {
        int row = bm + ww + mi * 16 + quad * 4 + r;
        int col = bn + wc + ni * 16 + l15;
        store_c(&C[(size_t)row * N + col], acc[mi][ni][r]);
      }
}

// ---------------- RoPE for q,k -> head-major layouts ----------------
__global__ void rope_qk(const __hip_bfloat16* __restrict__ QKV,
                        const float* __restrict__ cosp, const float* __restrict__ sinp,
                        __hip_bfloat16* __restrict__ Qh, __hip_bfloat16* __restrict__ Kh) {
  int s = blockIdx.y;
  int col = blockIdx.x * 256 + threadIdx.x;
  if (col >= 5120) return;
  const size_t base = (size_t)s * QKV_N;
  float x = __bfloat162float(QKV[base + col]);
  int dd = col & 127;
  float val;
  if (dd < 64) {
    float xp = __bfloat162float(QKV[base + col + 64]);
    val = x * cosp[s * 64 + dd] - xp * sinp[s * 64 + dd];
  } else {
    int f = dd - 64;
    float xp = __bfloat162float(QKV[base + col - 64]);
    val = x * cosp[s * 64 + f] + xp * sinp[s * 64 + f];
  }
  if (col < HID) {
    int h = col >> 7;
    Qh[((size_t)h * S_LEN + s) * HD + dd] = __float2bfloat16(val);
  } else {
    int h = (col - HID) >> 7;
    Kh[((size_t)h * S_LEN + s) * HD + dd] = __float2bfloat16(val);
  }
}

// ---------------- V transpose: QKV[s][5120+h*128+d] -> Vt[h][d][s] ----------------
__global__ void v_transpose(const __hip_bfloat16* __restrict__ QKV, __hip_bfloat16* __restrict__ Vt) {
  __shared__ ushort tile[64][130];
  int h = blockIdx.y;
  int s0 = blockIdx.x * 64;
  int t = threadIdx.x;
  const ushort* src = (const ushort*)QKV;
#pragma unroll
  for (int i = 0; i < 32; ++i) {
    int flat = i * 256 + t;
    int r = flat >> 7, c = flat & 127;
    tile[r][c] = src[(size_t)(s0 + r) * QKV_N + 5120 + h * 128 + c];
  }
  __syncthreads();
  ushort* dst = (ushort*)Vt;
#pragma unroll
  for (int i = 0; i < 8; ++i) {
    int g = i * 256 + t;
    int d = g >> 4, j4 = (g & 15) * 4;
    ushort4 o;
    o.x = tile[j4][d]; o.y = tile[j4 + 1][d]; o.z = tile[j4 + 2][d]; o.w = tile[j4 + 3][d];
    *(ushort4*)&dst[((size_t)h * HD + d) * S_LEN + s0 + j4] = o;
  }
}

// ---------------- flash attention v3 ----------------
// 32 q-rows/wave, K-step 64, K cooperatively staged (dbuf, swizzled, async), V direct global.
__global__ __launch_bounds__(256, 2) void attn(const __hip_bfloat16* __restrict__ Qh,
                                               const __hip_bfloat16* __restrict__ Kh,
                                               const __hip_bfloat16* __restrict__ Vt,
                                               __hip_bfloat16* __restrict__ AO) {
  // Ks[b][row][chunk c of 8 shorts] holds K global chunk c^(row&15)
  __shared__ __align__(16) ushort Ks[2][64][128];
  __shared__ __align__(16) ushort P[4][32][72];   // stride 72 shorts = 144B (16B aligned)
  const int bi   = blockIdx.x;                    // 0..511
  const int head = bi & 31;
  const int slot = (bi >> 5) & 7;
  const int qt   = (bi >= 256) ? (2 * slot) : (15 - 2 * slot);  // pair heavy+light per CU
  const int wave = threadIdx.x >> 6;
  const int lane = threadIdx.x & 63;
  const int l15 = lane & 15, quad = lane >> 4;
  const int q0 = qt * 128 + wave * 32;            // wave's 32 q rows
  const int hk = head & 7;
  const ushort* Qu = (const ushort*)Qh + (size_t)head * S_LEN * HD;
  const ushort* Ku = (const ushort*)Kh + (size_t)hk * S_LEN * HD;
  const ushort* Vu = (const ushort*)Vt + (size_t)hk * HD * S_LEN;

  // staging constants: wave stages rows [wave*16, wave*16+16), 4 issues x 4 rows x 256B
  const int rr4  = lane >> 4;                     // 0..3 row within issue
  const int cc16 = lane & 15;                     // LDS chunk

  short8 qf[2][4];
#pragma unroll
  for (int mt = 0; mt < 2; ++mt)
#pragma unroll
    for (int kd = 0; kd < 4; ++kd)
      qf[mt][kd] = *(const short8*)(Qu + (size_t)(q0 + mt * 16 + l15) * HD + kd * 32 + quad * 8);

  floatx4 o[2][8] = {};
  float mst[2][4], lsum[2][4];
#pragma unroll
  for (int mt = 0; mt < 2; ++mt)
#pragma unroll
    for (int r = 0; r < 4; ++r) { mst[mt][r] = -1e30f; lsum[mt][r] = 0.f; }

  const float scale = 0.08838834764831845f;
  const int nsteps = 2 * (qt + 1);
  const int jendw = q0 + 32;

  auto stage = [&](int b, int j0) {
#pragma unroll
    for (int e = 0; e < 4; ++e) {
      int rt = e * 4 + rr4;                        // 0..15 within wave's 16 rows
      int gc = cc16 ^ rt;                          // global chunk ((wave*16)%16==0)
      async_copy16(Ku + (size_t)(j0 + wave * 16 + rt) * HD + gc * 8,
                   &Ks[b][wave * 16 + e * 4][0]);
    }
  };
  stage(0, 0);

  for (int s = 0; s < nsteps; ++s) {
    const int j0 = s * 64;
    __syncthreads();
    if (s + 1 < nsteps) stage((s + 1) & 1, (s + 1) * 64);
    if (j0 >= jendw) continue;                     // wave-uniform; still hits barriers
    const int b = s & 1;

    // issue first-half V loads early so L2 latency hides under QK+softmax
    short8 vf0[8];
#pragma unroll
    for (int t = 0; t < 8; ++t)
      vf0[t] = *(const short8*)(Vu + (size_t)(t * 16 + l15) * S_LEN + j0 + quad * 8);

    // QK^T from swizzled LDS
    floatx4 sc[2][4];
#pragma unroll
    for (int mt = 0; mt < 2; ++mt)
#pragma unroll
      for (int nt = 0; nt < 4; ++nt) sc[mt][nt] = floatx4{0.f, 0.f, 0.f, 0.f};
#pragma unroll
    for (int nt = 0; nt < 4; ++nt) {
      short8 kf[4];
#pragma unroll
      for (int kd = 0; kd < 4; ++kd)
        kf[kd] = *(const short8*)&Ks[b][nt * 16 + l15][((kd * 4 + quad) ^ l15) * 8];
#pragma unroll
      for (int mt = 0; mt < 2; ++mt)
#pragma unroll
        for (int kd = 0; kd < 4; ++kd)
          sc[mt][nt] = __builtin_amdgcn_mfma_f32_16x16x32_bf16(qf[mt][kd], kf[kd], sc[mt][nt], 0, 0, 0);
    }

    const bool domask = (j0 + 64 > q0);            // only the diagonal step per wave
#pragma unroll
    for (int mt = 0; mt < 2; ++mt)
#pragma unroll
      for (int r = 0; r < 4; ++r) {
        const int row = q0 + mt * 16 + quad * 4 + r;
        float v[4];
#pragma unroll
        for (int nt = 0; nt < 4; ++nt) {
          float x = sc[mt][nt][r] * scale;
          if (domask && (j0 + nt * 16 + l15 > row)) x = -1e30f;
          v[nt] = x;
        }
        float vm = fmaxf(fmaxf(v[0], v[1]), fmaxf(v[2], v[3]));
        vm = fmaxf(vm, __shfl_xor(vm, 1));
        vm = fmaxf(vm, __shfl_xor(vm, 2));
        vm = fmaxf(vm, __shfl_xor(vm, 4));
        vm = fmaxf(vm, __shfl_xor(vm, 8));
        const float mnew = fmaxf(mst[mt][r], vm);
        const float alpha = __expf(mst[mt][r] - mnew);
        float ps = 0.f;
#pragma unroll
        for (int nt = 0; nt < 4; ++nt) {
          float p = __expf(v[nt] - mnew);
          ps += p;
          P[wave][mt * 16 + quad * 4 + r][nt * 16 + l15] = f2bu(p);
        }
        ps += __shfl_xor(ps, 1);
        ps += __shfl_xor(ps, 2);
        ps += __shfl_xor(ps, 4);
        ps += __shfl_xor(ps, 8);
        lsum[mt][r] = lsum[mt][r] * alpha + ps;
        mst[mt][r] = mnew;
#pragma unroll
        for (int t = 0; t < 8; ++t) o[mt][t][r] *= alpha;
      }

    // second-half V loads
    short8 vf1[8];
#pragma unroll
    for (int t = 0; t < 8; ++t)
      vf1[t] = *(const short8*)(Vu + (size_t)(t * 16 + l15) * S_LEN + j0 + 32 + quad * 8);

    asm volatile("s_waitcnt lgkmcnt(0)" ::: "memory");
    short8 pf[2][2];
#pragma unroll
    for (int mt = 0; mt < 2; ++mt)
#pragma unroll
      for (int hh = 0; hh < 2; ++hh)
        pf[mt][hh] = *(const short8*)&P[wave][mt * 16 + l15][hh * 32 + quad * 8];
#pragma unroll
    for (int t = 0; t < 8; ++t)
#pragma unroll
      for (int mt = 0; mt < 2; ++mt) {
        o[mt][t] = __builtin_amdgcn_mfma_f32_16x16x32_bf16(pf[mt][0], vf0[t], o[mt][t], 0, 0, 0);
        o[mt][t] = __builtin_amdgcn_mfma_f32_16x16x32_bf16(pf[mt][1], vf1[t], o[mt][t], 0, 0, 0);
      }
  }

#pragma unroll
  for (int mt = 0; mt < 2; ++mt)
#pragma unroll
    for (int r = 0; r < 4; ++r) {
      const int row = q0 + mt * 16 + quad * 4 + r;
      const float inv = 1.0f / lsum[mt][r];
#pragma unroll
      for (int t = 0; t < 8; ++t)
        AO[(size_t)row * HID + head * HD + t * 16 + l15] = __float2bfloat16(o[mt][t][r] * inv);
    }
}

extern "C" void kernel_launch(void* const* d_in, const int* in_sizes, int n_in,
                              void* d_out, int out_size, void* d_ws, size_t ws_size,
                              hipStream_t stream) {
  const float* x    = (const float*)d_in[0];
  const float* wq   = (const float*)d_in[1];
  const float* wk   = (const float*)d_in[2];
  const float* wv   = (const float*)d_in[3];
  const float* wo   = (const float*)d_in[4];
  const float* cosp = (const float*)d_in[5];
  const float* sinp = (const float*)d_in[6];
  float* out = (float*)d_out;

  char* ws = (char*)d_ws;
  size_t off = 0;
  auto alloc = [&](size_t bytes) { char* p = ws + off; off += (bytes + 255) & ~255ull; return p; };
  __hip_bfloat16* Xb   = (__hip_bfloat16*)alloc((size_t)S_LEN * KDIM * 2);
  __hip_bfloat16* Wqkv = (__hip_bfloat16*)alloc((size_t)QKV_N * KDIM * 2);
  __hip_bfloat16* Wob  = (__hip_bfloat16*)alloc((size_t)HID * HID * 2);
  __hip_bfloat16* QKVb = (__hip_bfloat16*)alloc((size_t)S_LEN * QKV_N * 2);
  __hip_bfloat16* Qh   = (__hip_bfloat16*)alloc((size_t)NH * S_LEN * HD * 2);
  __hip_bfloat16* Kh   = (__hip_bfloat16*)alloc((size_t)NKV * S_LEN * HD * 2);
  __hip_bfloat16* Vt   = (__hip_bfloat16*)alloc((size_t)NKV * HD * S_LEN * 2);
  __hip_bfloat16* AO   = (__hip_bfloat16*)alloc((size_t)S_LEN * HID * 2);

  auto cvt = [&](const float* s, __hip_bfloat16* dpt, size_t n) {
    int n4 = (int)(n / 4);
    cvt_f32_bf16<<<dim3((n4 + 255) / 256), dim3(256), 0, stream>>>(s, dpt, n4);
  };
  cvt(x, Xb, (size_t)S_LEN * KDIM);
  cvt(wq, Wqkv, (size_t)HID * KDIM);
  cvt(wk, Wqkv + (size_t)HID * KDIM, (size_t)NKV * HD * KDIM);
  cvt(wv, Wqkv + (size_t)(HID + NKV * HD) * KDIM, (size_t)NKV * HD * KDIM);
  cvt(wo, Wob, (size_t)HID * HID);

  gemm_nt<__hip_bfloat16><<<dim3(QKV_N / 128, S_LEN / 128), dim3(256), 0, stream>>>(
      Xb, Wqkv, QKVb, S_LEN, QKV_N, KDIM);
  rope_qk<<<dim3(20, S_LEN), dim3(256), 0, stream>>>(QKVb, cosp, sinp, Qh, Kh);
  v_transpose<<<dim3(S_LEN / 64, NKV), dim3(256), 0, stream>>>(QKVb, Vt);
  attn<<<dim3(512), dim3(256), 0, stream>>>(Qh, Kh, Vt, AO);
  gemm_nt<float><<<dim3(HID / 128, S_LEN / 128), dim3(256), 0, stream>>>(
      AO, Wob, out, S_LEN, HID, KDIM);
}